// Round 6
// baseline (1047.520 us; speedup 1.0000x reference)
//
#include <hip/hip_runtime.h>
#include <hip/hip_bf16.h>
#include <math.h>

// Problem constants
#define BB 4
#define SS 4096
#define NN 256
#define DD 1024
#define GG 16
#define CC 64
#define EPS 1e-5f
#define SCALE 0.125f   // (D/G)^-0.5 = 64^-0.5

typedef __bf16 bf16_t;
typedef __bf16 bf16x8 __attribute__((ext_vector_type(8)));
typedef float f32x4 __attribute__((ext_vector_type(4)));

// ---------------- fp32 -> bf16 convert ----------------
__global__ void f2b_kernel(const float* __restrict__ in, bf16_t* __restrict__ out, int n) {
    int i = (blockIdx.x * blockDim.x + threadIdx.x) * 4;
    if (i < n) {
        f32x4 v = *(const f32x4*)&in[i];
        #pragma unroll
        for (int j = 0; j < 4; j++) out[i + j] = (bf16_t)v[j];
    }
}

// ---------------- mask dtype detect + canonicalize ----------------
// bool arrays may arrive as 1-byte bool or int32. If any of the first 4096
// 32-bit words is >1, the layout must be byte-packed bool.
__global__ void mask_detect(const unsigned int* __restrict__ m, int* __restrict__ flag) {
    __shared__ int any;
    if (threadIdx.x == 0) any = 0;
    __syncthreads();
    int found = 0;
    for (int i = threadIdx.x; i < 4096; i += 256)
        if (m[i] > 1u) found = 1;
    if (found) atomicOr(&any, 1);
    __syncthreads();
    if (threadIdx.x == 0) *flag = any;
}

__global__ void mask_canon(const void* __restrict__ m, const int* __restrict__ flag,
                           unsigned char* __restrict__ out) {
    int i = blockIdx.x * 256 + threadIdx.x;   // grid covers B*S = 16384
    int f = *flag;
    unsigned char v = f ? ((const unsigned char*)m)[i]
                        : (unsigned char)(((const int*)m)[i] != 0);
    out[i] = v ? 1 : 0;
}

// ---------------- LayerNorm (row = 1024), fp32 in, bf16 out ----------------
// mode 0: y = LN(x); mode 1: y = LN(x + add) (same layout); mode 2: y = LN(x + add[row*64 + (d&63)])
__global__ __launch_bounds__(256)
void ln_kernel(const float* __restrict__ x, const float* __restrict__ add, int mode,
               const float* __restrict__ w, const float* __restrict__ b,
               bf16_t* __restrict__ out)
{
    long row = blockIdx.x;
    int t = threadIdx.x;
    const float* xr = x + row * DD;
    f32x4 v = *(const f32x4*)&xr[t * 4];
    if (mode == 1) {
        f32x4 a = *(const f32x4*)&add[row * DD + t * 4];
        v += a;
    } else if (mode == 2) {
        f32x4 a = *(const f32x4*)&add[row * CC + ((t * 4) & (CC - 1))];
        v += a;
    }
    float s1 = v[0] + v[1] + v[2] + v[3];
    float s2 = v[0]*v[0] + v[1]*v[1] + v[2]*v[2] + v[3]*v[3];
    #pragma unroll
    for (int off = 32; off > 0; off >>= 1) {
        s1 += __shfl_down(s1, off);
        s2 += __shfl_down(s2, off);
    }
    __shared__ float red[8];
    int wid = t >> 6;
    if ((t & 63) == 0) { red[wid] = s1; red[4 + wid] = s2; }
    __syncthreads();
    float S1 = red[0] + red[1] + red[2] + red[3];
    float S2 = red[4] + red[5] + red[6] + red[7];
    float mu = S1 * (1.0f / DD);
    float var = S2 * (1.0f / DD) - mu * mu;
    float rs = rsqrtf(var + EPS);
    #pragma unroll
    for (int j = 0; j < 4; j++) {
        int d = t * 4 + j;
        float y = (v[j] - mu) * rs * w[d] + b[d];
        out[row * DD + d] = (bf16_t)y;
    }
}

// ---------------- bf16 transpose (per batch): in R x Cc -> out Cc x R ----------------
__global__ __launch_bounds__(256)
void transpose_bf16(const bf16_t* __restrict__ in, bf16_t* __restrict__ out, int R, int Cc)
{
    __shared__ bf16_t tile[32][33];
    int bz = blockIdx.z;
    int c0 = blockIdx.x * 32, r0 = blockIdx.y * 32;
    int tx = threadIdx.x & 31, ty = threadIdx.x >> 5;
    long base = (long)bz * R * Cc;
    #pragma unroll
    for (int ii = 0; ii < 4; ii++) {
        int rr = ty * 4 + ii;
        tile[rr][tx] = in[base + (long)(r0 + rr) * Cc + c0 + tx];
    }
    __syncthreads();
    #pragma unroll
    for (int ii = 0; ii < 4; ii++) {
        int rr = ty * 4 + ii;
        out[base + (long)(c0 + rr) * R + r0 + tx] = tile[tx][rr];
    }
}

// ---------------- GEMM: C[m][n] = sum_k A[m][k] * W[n][k]  (+bias, gelu, +resid) ----------------
// A: M x K bf16 row-major, W: N x K bf16 row-major. 64x64 tile, 256 threads, 4 waves (16 rows each).
__global__ __launch_bounds__(256)
void gemm_bt_kernel(const bf16_t* __restrict__ A, const bf16_t* __restrict__ W,
                    int M, int N, int K, long sA, long sW, long sC,
                    const float* __restrict__ bias, const float* __restrict__ resid, long sR,
                    float* __restrict__ outf, bf16_t* __restrict__ outb, int act_gelu)
{
    int bz = blockIdx.z;
    A += bz * sA;
    W += bz * sW;
    int m0 = blockIdx.x * 64, n0 = blockIdx.y * 64;
    __shared__ bf16_t As[64][40];   // +8 pad: 80B rows -> 2-way-max bank conflict, 16B aligned
    __shared__ bf16_t Ws[64][40];
    int t = threadIdx.x;
    int l = t & 63, wid = t >> 6, lo = l & 15, hi = l >> 4;
    f32x4 acc[4] = {};
    int row_s = t >> 2, kc8 = (t & 3) * 8;
    for (int k0 = 0; k0 < K; k0 += 32) {
        __syncthreads();
        *(bf16x8*)&As[row_s][kc8] = *(const bf16x8*)&A[(long)(m0 + row_s) * K + k0 + kc8];
        *(bf16x8*)&Ws[row_s][kc8] = *(const bf16x8*)&W[(long)(n0 + row_s) * K + k0 + kc8];
        __syncthreads();
        bf16x8 a = *(const bf16x8*)&As[wid * 16 + lo][hi * 8];
        #pragma unroll
        for (int c = 0; c < 4; c++) {
            bf16x8 w8 = *(const bf16x8*)&Ws[c * 16 + lo][hi * 8];
            acc[c] = __builtin_amdgcn_mfma_f32_16x16x32_bf16(a, w8, acc[c], 0, 0, 0);
        }
    }
    long cb = bz * sC;
    #pragma unroll
    for (int c = 0; c < 4; c++) {
        #pragma unroll
        for (int r = 0; r < 4; r++) {
            int mi = m0 + wid * 16 + hi * 4 + r;
            int ni = n0 + c * 16 + lo;
            float v = acc[c][r];
            if (bias) v += bias[ni];
            if (act_gelu) v = 0.5f * v * (1.0f + erff(v * 0.70710678118f));
            if (resid) v += resid[bz * sR + (long)mi * N + ni];
            if (outf) outf[cb + (long)mi * N + ni] = v;
            if (outb) outb[cb + (long)mi * N + ni] = (bf16_t)v;
        }
    }
}

// ---------------- Fused attention: scores + mask + softmax + attn-output + PV ----------------
// Grid: B*G*(N/64) blocks of 256 threads (4 waves, 16 q-rows each).
// Pass 1: online max/sum over all S (recompute QK^T). Pass 2: recompute scores, write
// normalized attn (masked -> 0), accumulate P@V with MFMA (V transposed through LDS).
__global__ __launch_bounds__(256)
void attn_kernel(const bf16_t* __restrict__ qp, const bf16_t* __restrict__ kp,
                 const bf16_t* __restrict__ vp, const unsigned char* __restrict__ mask,
                 float* __restrict__ attn_out, bf16_t* __restrict__ pv_out)
{
    int bz = blockIdx.x;
    int nt = bz & 3;            // N/64 = 4 tiles
    int g  = (bz >> 2) & 15;
    int b  = bz >> 6;
    int t = threadIdx.x;
    int l = t & 63, wid = t >> 6, lo = l & 15, hi = l >> 4;

    __shared__ bf16_t qs[64][72];   // 144B rows: 16B aligned, ~2-way conflicts on frag reads
    __shared__ bf16_t ks[64][72];
    __shared__ bf16_t vts[64][72];  // V transposed: vts[c][s]
    __shared__ bf16_t ps[64][72];   // P tile (bf16) for PV A-fragments

    // stage q tile (64 rows x 64 c)
    #pragma unroll
    for (int i = 0; i < 2; i++) {
        int idx = t + i * 256;
        int rowq = idx >> 3, cg = (idx & 7) * 8;
        *(bf16x8*)&qs[rowq][cg] =
            *(const bf16x8*)&qp[((long)(b * NN + nt * 64 + rowq)) * DD + g * 64 + cg];
    }
    __syncthreads();
    bf16x8 aq0 = *(const bf16x8*)&qs[wid * 16 + lo][hi * 8];
    bf16x8 aq1 = *(const bf16x8*)&qs[wid * 16 + lo][hi * 8 + 32];

    float m_run[4], l_run[4];
    #pragma unroll
    for (int r = 0; r < 4; r++) { m_run[r] = -1e30f; l_run[r] = 0.0f; }

    const long kbase = ((long)b * SS) * DD + g * 64;
    const unsigned char* mrow = mask + (long)b * SS;

    // ---- PASS 1: stats ----
    for (int s0 = 0; s0 < SS; s0 += 64) {
        __syncthreads();
        #pragma unroll
        for (int i = 0; i < 2; i++) {
            int idx = t + i * 256;
            int rowk = idx >> 3, cg = (idx & 7) * 8;
            *(bf16x8*)&ks[rowk][cg] = *(const bf16x8*)&kp[kbase + (long)(s0 + rowk) * DD + cg];
        }
        __syncthreads();
        float vv[4][4];
        float cmax[4] = {-1e30f, -1e30f, -1e30f, -1e30f};
        #pragma unroll
        for (int st = 0; st < 4; st++) {
            f32x4 sc = (f32x4){0, 0, 0, 0};
            bf16x8 b0 = *(const bf16x8*)&ks[st * 16 + lo][hi * 8];
            bf16x8 b1 = *(const bf16x8*)&ks[st * 16 + lo][hi * 8 + 32];
            sc = __builtin_amdgcn_mfma_f32_16x16x32_bf16(aq0, b0, sc, 0, 0, 0);
            sc = __builtin_amdgcn_mfma_f32_16x16x32_bf16(aq1, b1, sc, 0, 0, 0);
            bool mk = mrow[s0 + st * 16 + lo] != 0;
            #pragma unroll
            for (int r = 0; r < 4; r++) {
                float val = mk ? -1e30f : sc[r] * SCALE;
                vv[st][r] = val;
                cmax[r] = fmaxf(cmax[r], val);
            }
        }
        #pragma unroll
        for (int r = 0; r < 4; r++) {
            float cm = cmax[r];
            cm = fmaxf(cm, __shfl_xor(cm, 1));
            cm = fmaxf(cm, __shfl_xor(cm, 2));
            cm = fmaxf(cm, __shfl_xor(cm, 4));
            cm = fmaxf(cm, __shfl_xor(cm, 8));
            float mn = fmaxf(m_run[r], cm);
            float sum = 0.0f;
            #pragma unroll
            for (int st = 0; st < 4; st++) sum += __expf(vv[st][r] - mn);
            sum += __shfl_xor(sum, 1);
            sum += __shfl_xor(sum, 2);
            sum += __shfl_xor(sum, 4);
            sum += __shfl_xor(sum, 8);
            l_run[r] = l_run[r] * __expf(m_run[r] - mn) + sum;
            m_run[r] = mn;
        }
    }

    float rl[4];
    #pragma unroll
    for (int r = 0; r < 4; r++) rl[r] = 1.0f / l_run[r];

    f32x4 oacc[4] = {};

    // ---- PASS 2: normalized attn + PV ----
    for (int s0 = 0; s0 < SS; s0 += 64) {
        __syncthreads();
        #pragma unroll
        for (int i = 0; i < 2; i++) {
            int idx = t + i * 256;
            int rowk = idx >> 3, cg = (idx & 7) * 8;
            *(bf16x8*)&ks[rowk][cg] = *(const bf16x8*)&kp[kbase + (long)(s0 + rowk) * DD + cg];
        }
        {   // stage V transposed: vts[c][s_local]
            int c = t & 63, sb = t >> 6;
            #pragma unroll
            for (int i = 0; i < 16; i++) {
                int sl = sb * 16 + i;
                vts[c][sl] = vp[kbase + (long)(s0 + sl) * DD + c];
            }
        }
        __syncthreads();
        #pragma unroll
        for (int st = 0; st < 4; st++) {
            f32x4 sc = (f32x4){0, 0, 0, 0};
            bf16x8 b0 = *(const bf16x8*)&ks[st * 16 + lo][hi * 8];
            bf16x8 b1 = *(const bf16x8*)&ks[st * 16 + lo][hi * 8 + 32];
            sc = __builtin_amdgcn_mfma_f32_16x16x32_bf16(aq0, b0, sc, 0, 0, 0);
            sc = __builtin_amdgcn_mfma_f32_16x16x32_bf16(aq1, b1, sc, 0, 0, 0);
            int s_abs = s0 + st * 16 + lo;
            bool mk = mrow[s_abs] != 0;
            #pragma unroll
            for (int r = 0; r < 4; r++) {
                float p = mk ? 0.0f : __expf(sc[r] * SCALE - m_run[r]) * rl[r];
                int n_loc = wid * 16 + hi * 4 + r;
                int n_abs = nt * 64 + n_loc;
                attn_out[(((long)b * NN + n_abs) * GG + g) * SS + s_abs] = p;
                ps[n_loc][st * 16 + lo] = (bf16_t)p;
            }
        }
        __syncthreads();   // make ps visible (and order LDS ops) before PV fragment reads
        bf16x8 pa0 = *(const bf16x8*)&ps[wid * 16 + lo][hi * 8];
        bf16x8 pa1 = *(const bf16x8*)&ps[wid * 16 + lo][hi * 8 + 32];
        #pragma unroll
        for (int ct = 0; ct < 4; ct++) {
            bf16x8 vb0 = *(const bf16x8*)&vts[ct * 16 + lo][hi * 8];
            bf16x8 vb1 = *(const bf16x8*)&vts[ct * 16 + lo][hi * 8 + 32];
            oacc[ct] = __builtin_amdgcn_mfma_f32_16x16x32_bf16(pa0, vb0, oacc[ct], 0, 0, 0);
            oacc[ct] = __builtin_amdgcn_mfma_f32_16x16x32_bf16(pa1, vb1, oacc[ct], 0, 0, 0);
        }
    }

    // write PV result as bf16 (input to out-projection GEMM)
    #pragma unroll
    for (int ct = 0; ct < 4; ct++) {
        #pragma unroll
        for (int r = 0; r < 4; r++) {
            int n_abs = nt * 64 + wid * 16 + hi * 4 + r;
            int c = ct * 16 + lo;
            pv_out[((long)b * NN + n_abs) * DD + g * 64 + c] = (bf16_t)oacc[ct][r];
        }
    }
}

// ---------------- host launch ----------------
// Kernel order (stream-ordered; aliases rely on this):
//  1 mask_detect/canon   2 f2b x7           3 ln(q)->qln
//  4 ln(k)->bufA         5 gemm->kp         6 ln(v)->bufA      7 gemm->vp
//  8 gemm qln->qp        9 attn(qp,kp,vp)->out_attn,aout  [qln,qp,kp,vp,bufA dead after]
// 10 gemm aout->p1      11 ln(p1)->tb      12 transpose tb->tT [tb dead]
// 13 gemm reason ->p2   [tT,p1 dead]       14 ln(p2)->l3
// 15 gemm l3->h1 (gelu) [l3 dead]          16 gemm h1 (+p2) -> out_parts
extern "C" void kernel_launch(void* const* d_in, const int* in_sizes, int n_in,
                              void* d_out, int out_size, void* d_ws, size_t ws_size,
                              hipStream_t stream) {
    const float* feats  = (const float*)d_in[0];
    const float* parts  = (const float*)d_in[1];
    const float* qpos   = (const float*)d_in[2];
    const float* kpos   = (const float*)d_in[3];
    const void*  mask_raw = d_in[4];
    const float* ln_q_w = (const float*)d_in[5];
    const float* ln_q_b = (const float*)d_in[6];
    const float* ln_k_w = (const float*)d_in[7];
    const float* ln_k_b = (const float*)d_in[8];
    const float* ln_v_w = (const float*)d_in[9];
    const float* ln_v_b = (const float*)d_in[10];
    const float* wq     = (const float*)d_in[11];
    const float* wk     = (const float*)d_in[12];
    const float* wv     = (const float*)d_in[13];
    const float* w_proj = (const float*)d_in[14];
    const float* b_proj = (const float*)d_in[15];
    const float* r_ln_w = (const float*)d_in[16];
    const float* r_ln_b = (const float*)d_in[17];
    const float* reason_w = (const float*)d_in[18];
    const float* m_ln_w = (const float*)d_in[19];
    const float* m_ln_b = (const float*)d_in[20];
    const float* fc1_w  = (const float*)d_in[21];
    const float* fc1_b  = (const float*)d_in[22];
    const float* fc2_w  = (const float*)d_in[23];
    const float* fc2_b  = (const float*)d_in[24];

    float* out_parts = (float*)d_out;
    float* out_attn  = (float*)d_out + (long)BB * NN * DD;   // 1,048,576 floats

    const long DXD = (long)DD * DD;          // 1,048,576
    const long BND = (long)BB * NN * DD;     // 1,048,576
    const long BSD = (long)BB * SS * DD;     // 16,777,216

    char* ws = (char*)d_ws;
    size_t off = 0;
    auto alloc = [&](size_t bytes) -> void* {
        void* p = ws + off;
        off += (bytes + 255) & ~(size_t)255;
        return p;
    };

    // --- persistent-through-attn workspace (~80 MB total) ---
    bf16_t* wq_b  = (bf16_t*)alloc(DXD * 2);
    bf16_t* wk_b  = (bf16_t*)alloc(DXD * 2);
    bf16_t* wv_b  = (bf16_t*)alloc(DXD * 2);
    bf16_t* wpj_b = (bf16_t*)alloc(DXD * 2);
    bf16_t* f1w_b = (bf16_t*)alloc(DXD * 2);
    bf16_t* f2w_b = (bf16_t*)alloc(DXD * 2);
    bf16_t* rw_b  = (bf16_t*)alloc((long)NN * NN * 2);
    bf16_t* qln   = (bf16_t*)alloc(BND * 2);     // dead after step 8
    bf16_t* kp    = (bf16_t*)alloc(BSD * 2);     // dead after step 9
    bf16_t* vp    = (bf16_t*)alloc(BSD * 2);     // dead after step 9
    bf16_t* qp    = (bf16_t*)alloc(BND * 2);     // dead after step 9
    int*    mflag = (int*)alloc(256);
    unsigned char* mask8 = (unsigned char*)alloc(BB * SS);

    // --- lifetime aliases (no new workspace) ---
    bf16_t* bufA = (bf16_t*)out_attn;            // LN staging; consumed before attn writes attn_out
    bf16_t* aout = qln;                          // written step 9, after qln dead
    float*  p1   = (float*)kp;                   // written step 10, after kp dead (4 MB < 32 MB)
    bf16_t* tT   = (bf16_t*)((char*)kp + BND * 4);   // written step 12 (2 MB, disjoint from p1)
    float*  p2   = (float*)vp;                   // written step 13, after vp dead
    bf16_t* tb   = (bf16_t*)((char*)vp + BND * 4);   // written step 11 (disjoint from p2)
    bf16_t* l3   = tb;                           // written step 14, after tb dead
    bf16_t* h1   = qp;                           // written step 15, after qp dead

    // mask canonicalization (bool-byte vs int32 robustness)
    mask_detect<<<1, 256, 0, stream>>>((const unsigned int*)mask_raw, mflag);
    mask_canon<<<BB * SS / 256, 256, 0, stream>>>(mask_raw, mflag, mask8);

    // weights -> bf16
    f2b_kernel<<<1024, 256, 0, stream>>>(wq, wq_b, DXD);
    f2b_kernel<<<1024, 256, 0, stream>>>(wk, wk_b, DXD);
    f2b_kernel<<<1024, 256, 0, stream>>>(wv, wv_b, DXD);
    f2b_kernel<<<1024, 256, 0, stream>>>(w_proj, wpj_b, DXD);
    f2b_kernel<<<1024, 256, 0, stream>>>(fc1_w, f1w_b, DXD);
    f2b_kernel<<<1024, 256, 0, stream>>>(fc2_w, f2w_b, DXD);
    f2b_kernel<<<64, 256, 0, stream>>>(reason_w, rw_b, NN * NN);

    // LN(q = parts + qpos broadcast) -> qln
    ln_kernel<<<BB * NN, 256, 0, stream>>>(parts, qpos, 2, ln_q_w, ln_q_b, qln);
    // LN(k = feats + kpos) -> bufA ; project -> kp
    ln_kernel<<<BB * SS, 256, 0, stream>>>(feats, kpos, 1, ln_k_w, ln_k_b, bufA);
    gemm_bt_kernel<<<dim3(256, 16, 1), 256, 0, stream>>>(bufA, wk_b, BB * SS, DD, DD,
        0, 0, 0, nullptr, nullptr, 0, nullptr, kp, 0);
    // LN(v = feats) -> bufA ; project -> vp
    ln_kernel<<<BB * SS, 256, 0, stream>>>(feats, nullptr, 0, ln_v_w, ln_v_b, bufA);
    gemm_bt_kernel<<<dim3(256, 16, 1), 256, 0, stream>>>(bufA, wv_b, BB * SS, DD, DD,
        0, 0, 0, nullptr, nullptr, 0, nullptr, vp, 0);
    // project q -> qp
    gemm_bt_kernel<<<dim3(16, 16, 1), 256, 0, stream>>>(qln, wq_b, BB * NN, DD, DD,
        0, 0, 0, nullptr, nullptr, 0, nullptr, qp, 0);

    // fused attention: writes attn output + PV result (aout aliases dead qln)
    attn_kernel<<<BB * GG * (NN / 64), 256, 0, stream>>>(qp, kp, vp, mask8, out_attn, aout);

    // out projection + residual: p1 = parts + aout @ w_proj^T + b_proj
    gemm_bt_kernel<<<dim3(16, 16, 1), 256, 0, stream>>>(aout, wpj_b, BB * NN, DD, DD,
        0, 0, 0, b_proj, parts, 0, p1, nullptr, 0);

    // reason: t = LN(p1); p2 = p1 + reason_w @ t  (per batch)
    ln_kernel<<<BB * NN, 256, 0, stream>>>(p1, nullptr, 0, r_ln_w, r_ln_b, tb);
    transpose_bf16<<<dim3(DD / 32, NN / 32, BB), 256, 0, stream>>>(tb, tT, NN, DD);
    gemm_bt_kernel<<<dim3(4, 16, BB), 256, 0, stream>>>(rw_b, tT, NN, DD, NN,
        0, (long)DD * NN, (long)NN * DD, nullptr, p1, (long)NN * DD, p2, nullptr, 0);

    // MLP: l3 = LN(p2); h1 = gelu(l3 @ fc1^T + b1); out_parts = p2 + h1 @ fc2^T + b2
    ln_kernel<<<BB * NN, 256, 0, stream>>>(p2, nullptr, 0, m_ln_w, m_ln_b, l3);
    gemm_bt_kernel<<<dim3(16, 16, 1), 256, 0, stream>>>(l3, f1w_b, BB * NN, DD, DD,
        0, 0, 0, fc1_b, nullptr, 0, nullptr, h1, 1);
    gemm_bt_kernel<<<dim3(16, 16, 1), 256, 0, stream>>>(h1, f2w_b, BB * NN, DD, DD,
        0, 0, 0, fc2_b, p2, 0, out_parts, nullptr, 0);
}